// Round 6
// baseline (1160.543 us; speedup 1.0000x reference)
//
#include <hip/hip_runtime.h>

// OctreeMaxUnpool: out[i*8 + c, k] = (indices[i,k] == c) ? data[nempty_idx[i], k] : 0
// num = 500000, C = 64. Output 1.024 GB; total traffic ~1.24 GB -> ~198 us @ 6.3 TB/s.
//
// R9: R7 (contiguous wave stores, -16.5 us) + R8 (nt stores, -12 us) leave the
// kernel at ~240 us = 5.2 TB/s vs 6.29 TB/s proven achievable. Write side is
// fully clean (amp 1.00 measured, 1KB/inst, evict-first). Last lever: the read
// side still allocates normally -- 128 MB once-streamed indices + ~87 MB
// gathered data competing in L2 with the transient write lines. This round:
// NON-TEMPORAL (evict-first) LOADS on all three input streams. indices is
// read exactly once (textbook nt); data reuse distance is ~one wave (sorted
// nempty_idx) so evict-first lines still serve those hits. Single variable
// vs R8. If null, the remaining ~35-40 us is intrinsic gather/turnaround cost
// -> roofline.

typedef float vfloat4 __attribute__((ext_vector_type(4)));
typedef int   vint4   __attribute__((ext_vector_type(4)));

constexpr int C4 = 16;      // float4s per row (C=64)
constexpr int NCHILD = 8;

__global__ __launch_bounds__(256) void octree_unpool_kernel(
    const vfloat4* __restrict__ data,      // [N, 16] as float4
    const vint4*   __restrict__ indices,   // [num, 16] as int4
    const int*     __restrict__ nempty,    // [num]
    vfloat4*       __restrict__ out,       // [num*8, 16] as float4
    int num)
{
    int i = (blockIdx.x * blockDim.x + threadIdx.x) >> 6;   // one wave per i
    if (i >= num) return;
    int l  = threadIdx.x & 63;
    int g  = l >> 4;        // child group: this lane handles children g and g+4
    int k4 = l & 15;        // float4 chunk within row

    int row = __builtin_nontemporal_load(&nempty[i]);            // wave-uniform
    vint4   idx4 = __builtin_nontemporal_load(&indices[i * C4 + k4]);
    vfloat4 d4   = __builtin_nontemporal_load(&data[row * C4 + k4]);

    vfloat4* base = out + (long long)i * (NCHILD * C4);

#pragma unroll
    for (int co = 0; co < 2; ++co) {
        int c = co * 4 + g;
        vfloat4 o;
        o.x = (idx4.x == c) ? d4.x : 0.0f;
        o.y = (idx4.y == c) ? d4.y : 0.0f;
        o.z = (idx4.z == c) ? d4.z : 0.0f;
        o.w = (idx4.w == c) ? d4.w : 0.0f;
        // 1 KB fully-contiguous wave store, evict-first
        __builtin_nontemporal_store(o, base + co * 64 + l);
    }
}

extern "C" void kernel_launch(void* const* d_in, const int* in_sizes, int n_in,
                              void* d_out, int out_size, void* d_ws, size_t ws_size,
                              hipStream_t stream) {
    const vfloat4* data    = (const vfloat4*)d_in[0];
    const vint4*   indices = (const vint4*)  d_in[1];
    const int*     nempty  = (const int*)    d_in[2];
    // d_in[3] = depth (unused)
    vfloat4* out = (vfloat4*)d_out;

    int num = in_sizes[2];                 // 500000
    long long total = (long long)num * 64; // one wave (64 threads) per i
    int block = 256;
    int grid = (int)((total + block - 1) / block);

    octree_unpool_kernel<<<grid, block, 0, stream>>>(data, indices, nempty, out, num);
}